// Round 7
// baseline (143.428 us; speedup 1.0000x reference)
//
#include <hip/hip_runtime.h>
#include <cstdint>

#define S_CNT 10000
#define R_CNT 10000
#define PG 1024            // p-groups
#define PROWS 49           // p-rows per group (1024*49 = 50176 >= 50000)
#define CAP 1216           // slots per group: E~977, sigma~31 -> +7.5 sigma (even!)
#define SPLIT 2            // compute blocks per group -> grid 2048 = exact residency
#define PACKED_OFF_B 16384
#define WS_NEED ((size_t)PACKED_OFF_B + 8ull * PG * CAP)

__device__ __forceinline__ unsigned bfpack(float a, float b) {
    unsigned ua = __float_as_uint(a), ub = __float_as_uint(b);
    ua = (ua + 0x7FFFu + ((ua >> 16) & 1u)) >> 16;       // round-to-nearest-even bf16
    ub = (ub + 0x7FFFu + ((ub >> 16) & 1u)) >> 16;
    return ua | (ub << 16);
}
__device__ __forceinline__ float blo(unsigned u) { return __uint_as_float(u << 16); }
__device__ __forceinline__ float bhi(unsigned u) { return __uint_as_float(u & 0xFFFF0000u); }

// ---- pass 0: zero the group cursors (1024 ints) ----
__global__ __launch_bounds__(256) void zero_kernel(int4* __restrict__ cur4) {
    cur4[threadIdx.x] = make_int4(0, 0, 0, 0);
}

// ---- pass 1: single-pass bin-by-p-group scatter (block reservation) ----
// record: w0 = s | t<<14 | dp<<20 | (idx&63)<<26 ; w1 = r | (idx>>6)<<14
__global__ __launch_bounds__(256) void bin_kernel(
    const int* __restrict__ X, int n, int* __restrict__ cursors,
    int2* __restrict__ packed,
    const float* __restrict__ se, const float* __restrict__ re,
    const float* __restrict__ pe, float* __restrict__ out)
{
    __shared__ int lhist[PG], lbase[PG], lcur[PG];
    const int tid = threadIdx.x;
    const long long base = (long long)blockIdx.x * 1024;

    #pragma unroll
    for (int k = 0; k < PG / 256; ++k) lhist[tid + 256 * k] = 0;
    __syncthreads();

    int4 xs[4];
    int  grp[4];
    #pragma unroll
    for (int it = 0; it < 4; ++it) {
        const long long i = base + it * 256 + tid;
        if (i < n) {
            xs[it] = *reinterpret_cast<const int4*>(X + 4 * i);
            grp[it] = xs[it].z / PROWS;
            atomicAdd(&lhist[grp[it]], 1);
        } else grp[it] = -1;
    }
    __syncthreads();
    #pragma unroll
    for (int k = 0; k < PG / 256; ++k) {
        const int b = tid + 256 * k;
        const int c = lhist[b];
        lbase[b] = c ? atomicAdd(&cursors[b], c) : 0;
        lcur[b] = 0;
    }
    __syncthreads();
    #pragma unroll
    for (int it = 0; it < 4; ++it) {
        const int g = grp[it];
        if (g < 0) continue;
        const unsigned i = (unsigned)(base + it * 256 + tid);
        const int rank = lbase[g] + atomicAdd(&lcur[g], 1);
        if (rank < CAP) {
            const unsigned dp = (unsigned)(xs[it].z - g * PROWS);
            packed[g * CAP + rank] = make_int2(
                (int)((unsigned)xs[it].x | ((unsigned)xs[it].w << 14) | (dp << 20) | ((i & 63u) << 26)),
                (int)((unsigned)xs[it].y | ((i >> 6) << 14)));
        } else {
            // statistically unreachable overflow: compute sample directly
            const long long st = (long long)xs[it].x + (long long)xs[it].w * S_CNT;
            const long long rt = (long long)xs[it].y + (long long)xs[it].w * R_CNT;
            const long long p  = xs[it].z;
            float acc = 0.f;
            for (int k = 0; k < 64; ++k)
                acc += se[st * 64 + k] * pe[p * 128 + k]
                     + re[rt * 64 + k] * pe[p * 128 + 64 + k];
            out[i] = 1.0f / (1.0f + __expf(-acc));
        }
    }
}

// ---- pass 2: compute. p in LDS (bf16, 12.5 KB); 4 samples/group/iter for MLP ----
__global__ __launch_bounds__(256, 8) void compute_kernel(
    const int* __restrict__ cursors, const int2* __restrict__ packed,
    const float* __restrict__ s_embeds, const float* __restrict__ r_embeds,
    const float* __restrict__ p_embeds, float* __restrict__ out)
{
    __shared__ __align__(16) unsigned plds[PROWS * 64];  // bf16x2, 12544 B
    const int g = blockIdx.x / SPLIT;
    const int q = blockIdx.x % SPLIT;
    const int cnt = min(cursors[g], CAP);
    if (cnt == 0) return;

    const int prow0 = g * PROWS;
    const int rows = min(PROWS, 50000 - prow0);
    const int nf4 = rows * 32;
    const float4* src = reinterpret_cast<const float4*>(p_embeds + (long long)prow0 * 128);
    for (int k = threadIdx.x; k < nf4; k += 256) {
        const float4 v = src[k];
        uint2 u;
        u.x = bfpack(v.x, v.y);
        u.y = bfpack(v.z, v.w);
        reinterpret_cast<uint2*>(plds)[k] = u;
    }
    __syncthreads();

    const int mid = (cnt / 2) & ~63;               // 64-aligned split point
    const int lo  = (q == 0) ? 0 : mid;
    const int end = (q == 0) ? mid : cnt;
    if (lo >= end) return;

    const int gl = threadIdx.x >> 4;   // group 0..15
    const int l  = threadIdx.x & 15;   // lane in group
    const int2* pk = packed + g * CAP;

    for (int sb = lo; sb < end; sb += 64) {
        const int j0 = sb + gl * 4;
        int2 rec[4];
        if (j0 + 3 < end) {            // fast path: one 16B + one 16B load, aligned
            const int4 w01 = *reinterpret_cast<const int4*>(pk + j0);
            const int4 w23 = *reinterpret_cast<const int4*>(pk + j0 + 2);
            rec[0] = make_int2(w01.x, w01.y); rec[1] = make_int2(w01.z, w01.w);
            rec[2] = make_int2(w23.x, w23.y); rec[3] = make_int2(w23.z, w23.w);
        } else {                       // tail: clamped scalar loads (never reads garbage)
            #pragma unroll
            for (int k = 0; k < 4; ++k) rec[k] = pk[min(j0 + k, end - 1)];
        }

        int st[4], rt[4], dp[4], idx[4];
        #pragma unroll
        for (int k = 0; k < 4; ++k) {
            const unsigned w0 = (unsigned)rec[k].x, w1 = (unsigned)rec[k].y;
            const int s = w0 & 0x3FFF;
            const int t = (w0 >> 14) & 0x3F;
            dp[k]  = (w0 >> 20) & 0x3F;
            idx[k] = (int)((w0 >> 26) | ((w1 >> 14) << 6));
            const int r = w1 & 0x3FFF;
            st[k] = s + t * S_CNT;
            rt[k] = r + t * R_CNT;
        }

        // issue all 8 independent gathers (32-bit voffsets) before any use
        float4 se[4], re[4];
        #pragma unroll
        for (int k = 0; k < 4; ++k)
            se[k] = *reinterpret_cast<const float4*>(s_embeds + (unsigned)st[k] * 64u + l * 4);
        #pragma unroll
        for (int k = 0; k < 4; ++k)
            re[k] = *reinterpret_cast<const float4*>(r_embeds + (unsigned)rt[k] * 64u + l * 4);

        float acc[4];
        #pragma unroll
        for (int k = 0; k < 4; ++k) {
            const int pb = dp[k] * 64;
            const uint2 upl = *reinterpret_cast<const uint2*>(&plds[pb + l * 2]);
            const uint2 uph = *reinterpret_cast<const uint2*>(&plds[pb + 32 + l * 2]);
            acc[k] = se[k].x * blo(upl.x) + se[k].y * bhi(upl.x)
                   + se[k].z * blo(upl.y) + se[k].w * bhi(upl.y)
                   + re[k].x * blo(uph.x) + re[k].y * bhi(uph.x)
                   + re[k].z * blo(uph.y) + re[k].w * bhi(uph.y);
        }

        #pragma unroll
        for (int k = 0; k < 4; ++k) {
            acc[k] += __shfl_xor(acc[k], 1, 64);
            acc[k] += __shfl_xor(acc[k], 2, 64);
            acc[k] += __shfl_xor(acc[k], 4, 64);
            acc[k] += __shfl_xor(acc[k], 8, 64);
        }

        if (l == 0) {
            #pragma unroll
            for (int k = 0; k < 4; ++k)
                if (j0 + k < end) out[idx[k]] = 1.0f / (1.0f + __expf(-acc[k]));
        }
    }
}

// ---- fallback: direct kernel (only if workspace too small) ----
__global__ __launch_bounds__(256) void direct_kernel(
    const int* __restrict__ X,
    const float* __restrict__ s_embeds, const float* __restrict__ r_embeds,
    const float* __restrict__ p_embeds, float* __restrict__ out, int n) {
    const int g = threadIdx.x >> 4;
    const int l = threadIdx.x & 15;
    const int i = blockIdx.x * 16 + g;
    if (i >= n) return;
    const int4 xi = *reinterpret_cast<const int4*>(X + 4ll * i);
    const long long st = (long long)xi.x + (long long)xi.w * S_CNT;
    const long long rt = (long long)xi.y + (long long)xi.w * R_CNT;
    const long long p  = xi.z;
    const float4 se = *reinterpret_cast<const float4*>(s_embeds + st * 64 + l * 4);
    const float4 re = *reinterpret_cast<const float4*>(r_embeds + rt * 64 + l * 4);
    const float4 pl = *reinterpret_cast<const float4*>(p_embeds + p * 128 + l * 4);
    const float4 ph = *reinterpret_cast<const float4*>(p_embeds + p * 128 + 64 + l * 4);
    float acc = se.x * pl.x + se.y * pl.y + se.z * pl.z + se.w * pl.w
              + re.x * ph.x + re.y * ph.y + re.z * ph.z + re.w * ph.w;
    acc += __shfl_xor(acc, 1, 64);
    acc += __shfl_xor(acc, 2, 64);
    acc += __shfl_xor(acc, 4, 64);
    acc += __shfl_xor(acc, 8, 64);
    if (l == 0) out[i] = 1.0f / (1.0f + __expf(-acc));
}

extern "C" void kernel_launch(void* const* d_in, const int* in_sizes, int n_in,
                              void* d_out, int out_size, void* d_ws, size_t ws_size,
                              hipStream_t stream) {
    const int*   X        = (const int*)d_in[0];
    const float* s_embeds = (const float*)d_in[1];
    const float* r_embeds = (const float*)d_in[2];
    const float* p_embeds = (const float*)d_in[3];
    float* out = (float*)d_out;
    const int n = in_sizes[0] / 4;

    if (ws_size < WS_NEED) {
        direct_kernel<<<(n + 15) / 16, 256, 0, stream>>>(
            X, s_embeds, r_embeds, p_embeds, out, n);
        return;
    }

    int* cursors = (int*)d_ws;
    int2* packed = reinterpret_cast<int2*>((char*)d_ws + PACKED_OFF_B);

    zero_kernel<<<1, 256, 0, stream>>>(reinterpret_cast<int4*>(cursors));
    bin_kernel<<<(n + 1023) / 1024, 256, 0, stream>>>(
        X, n, cursors, packed, s_embeds, r_embeds, p_embeds, out);
    compute_kernel<<<PG * SPLIT, 256, 0, stream>>>(
        cursors, packed, s_embeds, r_embeds, p_embeds, out);
}